// Round 2
// baseline (16738.292 us; speedup 1.0000x reference)
//
#include <hip/hip_runtime.h>
#include <hip/hip_bf16.h>

typedef __bf16 bf16x8 __attribute__((ext_vector_type(8)));
typedef __bf16 bf16x4 __attribute__((ext_vector_type(4)));
typedef float  f32x4  __attribute__((ext_vector_type(4)));

__device__ __forceinline__ float sigmoidf_(float x) { return 1.0f / (1.0f + expf(-x)); }

// Convert 8 consecutive fp32 -> bf16x8 fragment (16B-aligned source).
__device__ __forceinline__ bf16x8 cvt8(const float* p) {
    f32x4 a = *(const f32x4*)p;
    f32x4 b = *(const f32x4*)(p + 4);
    bf16x8 r;
    r[0] = (__bf16)a[0]; r[1] = (__bf16)a[1]; r[2] = (__bf16)a[2]; r[3] = (__bf16)a[3];
    r[4] = (__bf16)b[0]; r[5] = (__bf16)b[1]; r[6] = (__bf16)b[2]; r[7] = (__bf16)b[3];
    return r;
}

// ---------------------------------------------------------------------------
// B=64, T=512, I=1024, H=1024, 4H=4096.  ALL I/O IS FP32.
// PG (pre-gates, bf16, (T,B,4H) = 256 MiB) lives in the FIRST 256 MiB of
// d_out (nothing writes d_out until k_finalize/k_tail at the end).
// ws: h_hist bf16 (T,B,H) 64 MiB | Whh_bf 8 MiB | hf0,hf1,hb0,hb1 bf16 | cf,cb fp32
// ---------------------------------------------------------------------------

__global__ __launch_bounds__(256) void k_cvt_whh(const float* __restrict__ src,
                                                 __bf16* __restrict__ dst) {
    int i = blockIdx.x * 256 + threadIdx.x;   // 1,048,576 threads x 4 elems
    f32x4 v = ((const f32x4*)src)[i];
    bf16x4 o;
    o[0] = (__bf16)v[0]; o[1] = (__bf16)v[1]; o[2] = (__bf16)v[2]; o[3] = (__bf16)v[3];
    ((bf16x4*)dst)[i] = o;
}

__global__ __launch_bounds__(256) void k_init(
    const float* __restrict__ h0f, const float* __restrict__ c0f,
    const float* __restrict__ h0b, const float* __restrict__ c0b,
    __bf16* __restrict__ hf, __bf16* __restrict__ hb,
    float* __restrict__ cf, float* __restrict__ cb)
{
    int i = blockIdx.x * 256 + threadIdx.x;   // 65536
    hf[i] = (__bf16)h0f[i];
    hb[i] = (__bf16)h0b[i];
    cf[i] = c0f[i];
    cb[i] = c0b[i];
}

// PG[t][b][gc] = bias[gc] + sum_i x[b][t][i] * Wih[gc][i]   (bf16 MFMA, fp32 acc)
// grid (64 colblocks, 512 t), 4 waves; wave w -> 16 cols; inline fp32->bf16 cvt.
__global__ __launch_bounds__(256) void k_pregemm(
    const float* __restrict__ x,     // (B,T,I) fp32
    const float* __restrict__ Wih,   // (4H,I) fp32
    const float* __restrict__ bih, const float* __restrict__ bhh,
    __bf16* __restrict__ PG)
{
    const int t    = blockIdx.y;
    const int w    = threadIdx.x >> 6;
    const int lane = threadIdx.x & 63;
    const int m    = lane & 15;
    const int quad = lane >> 4;
    const int col  = blockIdx.x * 64 + w * 16 + m;

    f32x4 acc[4] = {};
    const float* Brow = Wih + col * 1024 + quad * 8;
    const float* Arow = x + (m * 512 + t) * 1024 + quad * 8;  // row b = rt*16+m

    for (int kb = 0; kb < 1024; kb += 32) {
        bf16x8 bfrag = cvt8(Brow + kb);
#pragma unroll
        for (int rt = 0; rt < 4; rt++) {
            bf16x8 afrag = cvt8(Arow + rt * 8388608 + kb);  // rt*16*512*1024
            acc[rt] = __builtin_amdgcn_mfma_f32_16x16x32_bf16(afrag, bfrag, acc[rt], 0, 0, 0);
        }
    }

    const float bias = bih[col] + bhh[col];
    __bf16* pgt = PG + (long)t * 262144;   // 64*4096
#pragma unroll
    for (int rt = 0; rt < 4; rt++) {
#pragma unroll
        for (int r = 0; r < 4; r++) {
            int b = rt * 16 + quad * 4 + r;   // C row = quad*4 + reg (verified layout)
            pgt[b * 4096 + col] = (__bf16)(acc[rt][r] + bias);
        }
    }
}

// One recurrence step, both cells. 128 blocks: cell=blk>>6, j0=(blk&63)*16.
// Wave w computes gate section w for cols j0..j0+15 (K=1024), then fused cell.
__global__ __launch_bounds__(256) void k_step(
    const __bf16* __restrict__ PG,
    const __bf16* __restrict__ Whh,
    const __bf16* __restrict__ h_in_f, const __bf16* __restrict__ h_in_b,
    __bf16* __restrict__ h_out_f, __bf16* __restrict__ h_out_b,
    float* __restrict__ c_f, float* __restrict__ c_b,
    __bf16* __restrict__ h_hist, int t)
{
    __shared__ float lds[4][64][17];

    const int cell = blockIdx.x >> 6;
    const int j0   = (blockIdx.x & 63) * 16;
    const __bf16* h_in  = cell ? h_in_b  : h_in_f;
    __bf16*       h_out = cell ? h_out_b : h_out_f;
    float*        c_st  = cell ? c_b     : c_f;
    const int t_pg = cell ? (511 - t) : t;

    const int w    = threadIdx.x >> 6;
    const int lane = threadIdx.x & 63;
    const int m    = lane & 15;
    const int quad = lane >> 4;
    const int gc   = w * 1024 + j0 + m;   // gate column (i,f,g,o sections)

    f32x4 acc[4] = {};
    const __bf16* Brow = Whh + gc * 1024 + quad * 8;
    const __bf16* Arow = h_in + m * 1024 + quad * 8;

    for (int kb = 0; kb < 1024; kb += 32) {
        bf16x8 bfrag = *(const bf16x8*)(Brow + kb);
#pragma unroll
        for (int rt = 0; rt < 4; rt++) {
            bf16x8 afrag = *(const bf16x8*)(Arow + rt * 16384 + kb);  // rt*16*1024
            acc[rt] = __builtin_amdgcn_mfma_f32_16x16x32_bf16(afrag, bfrag, acc[rt], 0, 0, 0);
        }
    }

    const __bf16* pgt = PG + (long)t_pg * 262144;
#pragma unroll
    for (int rt = 0; rt < 4; rt++) {
#pragma unroll
        for (int r = 0; r < 4; r++) {
            int b = rt * 16 + quad * 4 + r;
            lds[w][b][m] = acc[rt][r] + (float)pgt[b * 4096 + gc];
        }
    }
    __syncthreads();

    for (int e = threadIdx.x; e < 1024; e += 256) {
        const int b  = e >> 4;
        const int jj = e & 15;
        const float ig = sigmoidf_(lds[0][b][jj]);
        const float fg = sigmoidf_(lds[1][b][jj]);
        const float gg = tanhf(lds[2][b][jj]);
        const float og = sigmoidf_(lds[3][b][jj]);
        const int sidx = b * 1024 + j0 + jj;
        const float c_new = fg * c_st[sidx] + ig * gg;
        const float h_new = og * tanhf(c_new);
        c_st[sidx] = c_new;
        const __bf16 hq = (__bf16)h_new;
        h_out[sidx] = hq;
        if (cell == 0) h_hist[((t << 6) + b) * 1024 + j0 + jj] = hq;  // (t,b,j)
    }
}

// output[b][t][j] = h_hist[t][b][j]; output[b][t][1024+j] = h_hist[t][63-b][j]
__global__ __launch_bounds__(256) void k_finalize(const __bf16* __restrict__ h_hist,
                                                  float* __restrict__ out) {
    int n = blockIdx.x * 256 + threadIdx.x;   // 4,194,304 threads x 8 j
    int j = (n & 127) * 8;
    int b = (n >> 7) & 63;
    int t = n >> 13;
    bf16x8 hf = *(const bf16x8*)(h_hist + ((t * 64 + b) << 10) + j);
    bf16x8 hr = *(const bf16x8*)(h_hist + ((t * 64 + (63 - b)) << 10) + j);
    float* o = out + (b * 512 + t) * 2048 + j;
#pragma unroll
    for (int k = 0; k < 8; k++) {
        o[k]        = (float)hf[k];
        o[1024 + k] = (float)hr[k];
    }
}

// h_i = concat(hf_final, hb_final), c_i = concat(cf, cb) at out+67108864 / +131072
__global__ __launch_bounds__(256) void k_tail(
    const __bf16* __restrict__ hf_fin, const __bf16* __restrict__ hb_fin,
    const float* __restrict__ cf, const float* __restrict__ cb,
    float* __restrict__ out)
{
    int n = blockIdx.x * 256 + threadIdx.x;   // 16384 threads x 8
    int j = (n & 255) * 8;
    int b = n >> 8;
    float* hi = out + 67108864 + b * 2048 + j;
    float* ci = hi + 131072;
    if (j < 1024) {
        bf16x8 h = *(const bf16x8*)(hf_fin + b * 1024 + j);
#pragma unroll
        for (int k = 0; k < 8; k++) { hi[k] = (float)h[k]; ci[k] = cf[b * 1024 + j + k]; }
    } else {
        int jj = j - 1024;
        bf16x8 h = *(const bf16x8*)(hb_fin + b * 1024 + jj);
#pragma unroll
        for (int k = 0; k < 8; k++) { hi[k] = (float)h[k]; ci[k] = cb[b * 1024 + jj + k]; }
    }
}

extern "C" void kernel_launch(void* const* d_in, const int* in_sizes, int n_in,
                              void* d_out, int out_size, void* d_ws, size_t ws_size,
                              hipStream_t stream) {
    const float* x    = (const float*)d_in[0];
    const float* Wih  = (const float*)d_in[1];
    const float* Whh  = (const float*)d_in[2];
    const float* bih  = (const float*)d_in[3];
    const float* bhh  = (const float*)d_in[4];
    // d_in[5..8] (backward weights) are unused by the reference (it passes the
    // forward weights to both cells).
    const float* h0f  = (const float*)d_in[9];
    const float* c0f  = (const float*)d_in[10];
    const float* h0b  = (const float*)d_in[11];
    const float* c0b  = (const float*)d_in[12];

    float*  out = (float*)d_out;
    __bf16* PG  = (__bf16*)d_out;   // first 256 MiB of d_out reused as PG scratch

    const size_t HHIST_B = 67108864;   // 512*64*1024 bf16
    const size_t WHH_B   = 8388608;    // 4096*1024 bf16
    const size_t NEEDED  = HHIST_B + WHH_B + 4 * 131072 + 2 * 262144;  // ~73 MiB
    if (ws_size < NEEDED) return;      // loud fail (absmax), no OOB

    char* ws = (char*)d_ws;
    __bf16* h_hist = (__bf16*)ws;
    __bf16* Whh_bf = (__bf16*)(ws + HHIST_B);
    __bf16* hf0    = (__bf16*)(ws + HHIST_B + WHH_B);
    __bf16* hf1    = hf0 + 65536;
    __bf16* hb0    = hf1 + 65536;
    __bf16* hb1    = hb0 + 65536;
    float*  cf     = (float*)(hb1 + 65536);
    float*  cb     = cf + 65536;

    k_cvt_whh<<<4096, 256, 0, stream>>>(Whh, Whh_bf);
    k_init<<<256, 256, 0, stream>>>(h0f, c0f, h0b, c0b, hf0, hb0, cf, cb);
    k_pregemm<<<dim3(64, 512), 256, 0, stream>>>(x, Wih, bih, bhh, PG);

    for (int t = 0; t < 512; t++) {
        __bf16* hinf  = (t & 1) ? hf1 : hf0;
        __bf16* houtf = (t & 1) ? hf0 : hf1;
        __bf16* hinb  = (t & 1) ? hb1 : hb0;
        __bf16* houtb = (t & 1) ? hb0 : hb1;
        k_step<<<128, 256, 0, stream>>>(PG, Whh_bf, hinf, hinb, houtf, houtb,
                                        cf, cb, h_hist, t);
    }
    // after t=511 (odd): final fwd h in hf0, final bwd h in hb0
    k_finalize<<<16384, 256, 0, stream>>>(h_hist, out);
    k_tail<<<64, 256, 0, stream>>>(hf0, hb0, cf, cb, out);
}